// Round 8
// baseline (41.450 us; speedup 1.0000x reference)
//
#include <hip/hip_runtime.h>
#include <math.h>

#define B_ 32
#define C_ 128
#define L_ 4096
#define G_ 8
#define ROWS (B_ * C_)   // 4096 rows of 4096 floats

typedef float fx4 __attribute__((ext_vector_type(4)));

// monotone map: float order -> unsigned order (finite + inf, no NaN here)
__device__ __forceinline__ unsigned fmap(float f) {
    unsigned b = __float_as_uint(f);
    return (b & 0x80000000u) ? ~b : (b | 0x80000000u);
}
__device__ __forceinline__ float funmap(unsigned u) {
    unsigned b = (u & 0x80000000u) ? (u ^ 0x80000000u) : ~u;
    return __uint_as_float(b);
}

// ---------------- Kernel 1: per-(b,c) row min/max, one wave per row ----------------
// 1024 blocks x 256 threads; wave w of block bid handles row 4*bid+w. Read-roofline.
__global__ __launch_bounds__(256) void k_minmax(const float* __restrict__ x,
                                                float* __restrict__ pmin,
                                                float* __restrict__ pmax) {
    const int tid = threadIdx.x;
    const int wave = tid >> 6, lane = tid & 63;
    const int r = blockIdx.x * 4 + wave;          // row index, 0..4095
    const fx4* xv = (const fx4*)x + (size_t)r * (L_ / 4);
    float vmin = INFINITY, vmax = -INFINITY;
#pragma unroll
    for (int i = 0; i < 16; ++i) {
        fx4 v = xv[i * 64 + lane];
        vmin = fminf(vmin, fminf(fminf(v[0], v[1]), fminf(v[2], v[3])));
        vmax = fmaxf(vmax, fmaxf(fmaxf(v[0], v[1]), fmaxf(v[2], v[3])));
    }
#pragma unroll
    for (int off = 32; off > 0; off >>= 1) {
        vmin = fminf(vmin, __shfl_down(vmin, off, 64));
        vmax = fmaxf(vmax, __shfl_down(vmax, off, 64));
    }
    if (lane == 0) {
        const int b = r >> 7, c = r & (C_ - 1);
        pmin[c * B_ + b] = vmin;
        pmax[c * B_ + b] = vmax;
    }
}

// ---------------- Kernel 2: latency-flat prep (1 block, 128 threads) ----------------
// No serial 128-loops: shuffle-butterfly range reduce + LDS-atomic bin stats.
// min/max are order-independent => bit-exact vs the reference's serial scans.
__global__ __launch_bounds__(128) void k_prep(const float* __restrict__ pmin,
                                              const float* __restrict__ pmax,
                                              const float* __restrict__ alpha,
                                              float* __restrict__ wq,    // [G_][C_]
                                              float* __restrict__ offv,  // [C_]
                                              float* __restrict__ scv,   // [G_]
                                              float* __restrict__ zpv) { // [G_]
    const int c = threadIdx.x; // 0..127 = channel
    __shared__ float smin[C_], smax[C_];
    __shared__ unsigned gminU[G_], gmaxU[G_];
    __shared__ float ssc[G_], szp[G_];
    __shared__ float red[4];   // rminN, rmaxN, rminX, rmaxX

    // per-channel reduce of 32 batch partials (vectorized) + INIT clamps
    const fx4* pn = (const fx4*)pmin + c * (B_ / 4);
    const fx4* px = (const fx4*)pmax + c * (B_ / 4);
    float a = INFINITY, b = -INFINITY;
#pragma unroll
    for (int i = 0; i < B_ / 4; ++i) {
        fx4 u = pn[i], v = px[i];
        a = fminf(a, fminf(fminf(u[0], u[1]), fminf(u[2], u[3])));
        b = fmaxf(b, fmaxf(fmaxf(v[0], v[1]), fmaxf(v[2], v[3])));
    }
    a = fminf(a, -4.0f);   // ch_min = min(.., INIT_MIN)
    b = fmaxf(b, 6.0f);    // ch_max = max(.., INIT_MAX)
    smin[c] = a; smax[c] = b;
    if (c < G_) { gminU[c] = 0xFFFFFFFFu; gmaxU[c] = 0u; }  // unreachable sentinels
    __syncthreads();

    // 64-lane shuffle butterfly over both halves -> global ranges of each 128-vector
    if (c < 64) {
        float mnN = fminf(smin[c], smin[c + 64]), mxN = fmaxf(smin[c], smin[c + 64]);
        float mnX = fminf(smax[c], smax[c + 64]), mxX = fmaxf(smax[c], smax[c + 64]);
#pragma unroll
        for (int off = 32; off > 0; off >>= 1) {
            mnN = fminf(mnN, __shfl_down(mnN, off, 64));
            mxN = fmaxf(mxN, __shfl_down(mxN, off, 64));
            mnX = fminf(mnX, __shfl_down(mnX, off, 64));
            mxX = fmaxf(mxX, __shfl_down(mxX, off, 64));
        }
        if (c == 0) { red[0] = mnN; red[1] = mxN; red[2] = mnX; red[3] = mxX; }
    }
    __syncthreads();

    const float rminN = red[0], rmaxN = red[1], rminX = red[2], rmaxX = red[3];
    const float divN = rmaxN - rminN, divX = rmaxX - rminX;
    float bN[G_ + 1], bX[G_ + 1];
#pragma unroll
    for (int m = 0; m <= G_; ++m) {
        // replicate: rmin + div * (m/8) in f32, exact order
        bN[m] = rminN + __fmul_rn(divN, (float)m * 0.125f);
        bX[m] = rminX + __fmul_rn(divX, (float)m * 0.125f);
    }
    // mark: ascending m, later bins overwrite shared edges
    int mN = 0, mX = 0;
#pragma unroll
    for (int m = 0; m < G_; ++m) {
        if (a >= bN[m] && a <= bN[m + 1]) mN = m + 1;
        if (b >= bX[m] && b <= bX[m + 1]) mX = m + 1;
    }
    // one LDS atomic per channel replaces the serial per-bin scans
    if (mN) atomicMin(&gminU[mN - 1], fmap(a));
    if (mX) atomicMax(&gmaxU[mX - 1], fmap(b));
    __syncthreads();

    if (c < G_) {
        unsigned u = gminU[c], v = gmaxU[c];
        const float left  = (u == 0xFFFFFFFFu) ? bN[c + 1] : funmap(u);  // empty-bin fallback
        const float right = (v == 0u)          ? bX[c + 1] : funmap(v);
        const float sc = 255.0f / fmaxf(right - left, 1e-8f);
        const float zp = rintf(__fmul_rn(sc, left)) + 128.0f;
        ssc[c] = sc; szp[c] = zp;
        scv[c] = sc; zpv[c] = zp;
    }
    __syncthreads();

    // softmax over G for channel c; fold w = sw/scale, off = sum w*zp
    float av[G_];
    float amax = -INFINITY;
#pragma unroll
    for (int g = 0; g < G_; ++g) { av[g] = alpha[g * C_ + c]; amax = fmaxf(amax, av[g]); }
    float sum = 0.0f;
#pragma unroll
    for (int g = 0; g < G_; ++g) { av[g] = expf(av[g] - amax); sum += av[g]; }
    float offc = 0.0f;
#pragma unroll
    for (int g = 0; g < G_; ++g) {
        float w = (av[g] / sum) / ssc[g];
        wq[g * C_ + c] = w;
        offc += w * szp[g];
    }
    offv[c] = offc;
}

// ---------------- Kernel 3: elementwise apply, one row per 128-thread block ----------------
// out[idx] = off[c] + sum_g w[g,c] * clamp(rint(s_g*x - zp_g), -128, 127)
// 4096 blocks x 128 threads (2 waves -> 16 blocks/CU = 32 waves resident).
// PLAIN cached stores (A/B vs round 7's nt stores): writes aggregate in L2
// dirty lines -> full-line HBM bursts, like the harness fill's 6.7 TB/s path.
__global__ __launch_bounds__(128) void k_apply(const float* __restrict__ x,
                                               const float* __restrict__ wq,
                                               const float* __restrict__ offv,
                                               const float* __restrict__ scv,
                                               const float* __restrict__ zpv,
                                               float* __restrict__ out) {
    const int c = blockIdx.x & (C_ - 1);          // row = b*C_ + c
    float s[G_], z[G_], w[G_];
#pragma unroll
    for (int g = 0; g < G_; ++g) {
        s[g] = scv[g];
        z[g] = zpv[g];
        w[g] = wq[g * C_ + c];
    }
    const float offc = offv[c];
    const size_t base = (size_t)blockIdx.x * (L_ / 4) + threadIdx.x;

    fx4 xv[8];
#pragma unroll
    for (int i = 0; i < 8; ++i)                   // issue all loads first
        xv[i] = ((const fx4*)x)[base + i * 128];

#pragma unroll
    for (int i = 0; i < 8; ++i) {
        fx4 rv;
#pragma unroll
        for (int k = 0; k < 4; ++k) {
            float acc = offc;
#pragma unroll
            for (int g = 0; g < G_; ++g) {
                float t = __fmul_rn(s[g], xv[i][k]) - z[g];  // no fma contraction
                float q = rintf(t);                          // round half-to-even
                q = fminf(fmaxf(q, -128.0f), 127.0f);        // -> v_med3 clamp
                acc = fmaf(w[g], q, acc);
            }
            rv[k] = acc;
        }
        ((fx4*)out)[base + i * 128] = rv;         // plain cached store
    }
}

extern "C" void kernel_launch(void* const* d_in, const int* in_sizes, int n_in,
                              void* d_out, int out_size, void* d_ws, size_t ws_size,
                              hipStream_t stream) {
    const float* x = (const float*)d_in[0];       // [32,128,4096]
    const float* alpha = (const float*)d_in[1];   // [8,128]
    float* out = (float*)d_out;
    float* ws = (float*)d_ws;

    float* pmin = ws;              // [C_*B_] = 4096
    float* pmax = ws + 4096;       // 4096
    float* wq   = ws + 8192;       // [G_*C_] = 1024
    float* offv = ws + 9216;       // 128
    float* scv  = ws + 9344;       // 8
    float* zpv  = ws + 9352;       // 8

    k_minmax<<<ROWS / 4, 256, 0, stream>>>(x, pmin, pmax);
    k_prep<<<1, 128, 0, stream>>>(pmin, pmax, alpha, wq, offv, scv, zpv);
    k_apply<<<ROWS, 128, 0, stream>>>(x, wq, offv, scv, zpv, out);
}

// Round 9
// 40.924 us; speedup vs baseline: 1.0128x; 1.0128x over previous
//
#include <hip/hip_runtime.h>
#include <math.h>

#define B_ 32
#define C_ 128
#define L_ 4096
#define G_ 8
#define ROWS (B_ * C_)   // 4096 rows of 4096 floats

typedef float fx4 __attribute__((ext_vector_type(4)));

// monotone map: float order -> unsigned order (finite + inf, no NaN here)
__device__ __forceinline__ unsigned fmap(float f) {
    unsigned b = __float_as_uint(f);
    return (b & 0x80000000u) ? ~b : (b | 0x80000000u);
}
__device__ __forceinline__ float funmap(unsigned u) {
    unsigned b = (u & 0x80000000u) ? (u ^ 0x80000000u) : ~u;
    return __uint_as_float(b);
}

// ---------------- Kernel 1: per-(b,c) row min/max, one wave per row ----------------
// 1024 blocks x 256 threads; wave w of block bid handles row 4*bid+w. Read-roofline.
__global__ __launch_bounds__(256) void k_minmax(const float* __restrict__ x,
                                                float* __restrict__ pmin,
                                                float* __restrict__ pmax) {
    const int tid = threadIdx.x;
    const int wave = tid >> 6, lane = tid & 63;
    const int r = blockIdx.x * 4 + wave;          // row index, 0..4095
    const fx4* xv = (const fx4*)x + (size_t)r * (L_ / 4);
    float vmin = INFINITY, vmax = -INFINITY;
#pragma unroll
    for (int i = 0; i < 16; ++i) {
        fx4 v = xv[i * 64 + lane];
        vmin = fminf(vmin, fminf(fminf(v[0], v[1]), fminf(v[2], v[3])));
        vmax = fmaxf(vmax, fmaxf(fmaxf(v[0], v[1]), fmaxf(v[2], v[3])));
    }
#pragma unroll
    for (int off = 32; off > 0; off >>= 1) {
        vmin = fminf(vmin, __shfl_down(vmin, off, 64));
        vmax = fmaxf(vmax, __shfl_down(vmax, off, 64));
    }
    if (lane == 0) {
        const int b = r >> 7, c = r & (C_ - 1);
        pmin[c * B_ + b] = vmin;
        pmax[c * B_ + b] = vmax;
    }
}

// ---------------- Kernel 2: latency-flat prep (1 block, 128 threads) ----------------
// No serial 128-loops: shuffle-butterfly range reduce + LDS-atomic bin stats.
// min/max are order-independent => bit-exact vs the reference's serial scans.
__global__ __launch_bounds__(128) void k_prep(const float* __restrict__ pmin,
                                              const float* __restrict__ pmax,
                                              const float* __restrict__ alpha,
                                              float* __restrict__ wq,    // [G_][C_]
                                              float* __restrict__ offv,  // [C_]
                                              float* __restrict__ scv,   // [G_]
                                              float* __restrict__ zpv) { // [G_]
    const int c = threadIdx.x; // 0..127 = channel
    __shared__ float smin[C_], smax[C_];
    __shared__ unsigned gminU[G_], gmaxU[G_];
    __shared__ float ssc[G_], szp[G_];
    __shared__ float red[4];   // rminN, rmaxN, rminX, rmaxX

    // per-channel reduce of 32 batch partials (vectorized) + INIT clamps
    const fx4* pn = (const fx4*)pmin + c * (B_ / 4);
    const fx4* px = (const fx4*)pmax + c * (B_ / 4);
    float a = INFINITY, b = -INFINITY;
#pragma unroll
    for (int i = 0; i < B_ / 4; ++i) {
        fx4 u = pn[i], v = px[i];
        a = fminf(a, fminf(fminf(u[0], u[1]), fminf(u[2], u[3])));
        b = fmaxf(b, fmaxf(fmaxf(v[0], v[1]), fmaxf(v[2], v[3])));
    }
    a = fminf(a, -4.0f);   // ch_min = min(.., INIT_MIN)
    b = fmaxf(b, 6.0f);    // ch_max = max(.., INIT_MAX)
    smin[c] = a; smax[c] = b;
    if (c < G_) { gminU[c] = 0xFFFFFFFFu; gmaxU[c] = 0u; }  // unreachable sentinels
    __syncthreads();

    // 64-lane shuffle butterfly over both halves -> global ranges of each 128-vector
    if (c < 64) {
        float mnN = fminf(smin[c], smin[c + 64]), mxN = fmaxf(smin[c], smin[c + 64]);
        float mnX = fminf(smax[c], smax[c + 64]), mxX = fmaxf(smax[c], smax[c + 64]);
#pragma unroll
        for (int off = 32; off > 0; off >>= 1) {
            mnN = fminf(mnN, __shfl_down(mnN, off, 64));
            mxN = fmaxf(mxN, __shfl_down(mxN, off, 64));
            mnX = fminf(mnX, __shfl_down(mnX, off, 64));
            mxX = fmaxf(mxX, __shfl_down(mxX, off, 64));
        }
        if (c == 0) { red[0] = mnN; red[1] = mxN; red[2] = mnX; red[3] = mxX; }
    }
    __syncthreads();

    const float rminN = red[0], rmaxN = red[1], rminX = red[2], rmaxX = red[3];
    const float divN = rmaxN - rminN, divX = rmaxX - rminX;
    float bN[G_ + 1], bX[G_ + 1];
#pragma unroll
    for (int m = 0; m <= G_; ++m) {
        // replicate: rmin + div * (m/8) in f32, exact order
        bN[m] = rminN + __fmul_rn(divN, (float)m * 0.125f);
        bX[m] = rminX + __fmul_rn(divX, (float)m * 0.125f);
    }
    // mark: ascending m, later bins overwrite shared edges
    int mN = 0, mX = 0;
#pragma unroll
    for (int m = 0; m < G_; ++m) {
        if (a >= bN[m] && a <= bN[m + 1]) mN = m + 1;
        if (b >= bX[m] && b <= bX[m + 1]) mX = m + 1;
    }
    // one LDS atomic per channel replaces the serial per-bin scans
    if (mN) atomicMin(&gminU[mN - 1], fmap(a));
    if (mX) atomicMax(&gmaxU[mX - 1], fmap(b));
    __syncthreads();

    if (c < G_) {
        unsigned u = gminU[c], v = gmaxU[c];
        const float left  = (u == 0xFFFFFFFFu) ? bN[c + 1] : funmap(u);  // empty-bin fallback
        const float right = (v == 0u)          ? bX[c + 1] : funmap(v);
        const float sc = 255.0f / fmaxf(right - left, 1e-8f);
        const float zp = rintf(__fmul_rn(sc, left)) + 128.0f;
        ssc[c] = sc; szp[c] = zp;
        scv[c] = sc; zpv[c] = zp;
    }
    __syncthreads();

    // softmax over G for channel c; fold w = sw/scale, off = sum w*zp
    float av[G_];
    float amax = -INFINITY;
#pragma unroll
    for (int g = 0; g < G_; ++g) { av[g] = alpha[g * C_ + c]; amax = fmaxf(amax, av[g]); }
    float sum = 0.0f;
#pragma unroll
    for (int g = 0; g < G_; ++g) { av[g] = expf(av[g] - amax); sum += av[g]; }
    float offc = 0.0f;
#pragma unroll
    for (int g = 0; g < G_; ++g) {
        float w = (av[g] / sum) / ssc[g];
        wq[g * C_ + c] = w;
        offc += w * szp[g];
    }
    offv[c] = offc;
}

// ---------------- Kernel 3: elementwise apply, one row per 128-thread block ----------------
// out = off[c] + sum_g w[g,c] * med3(rint(fma(s_g, x, -zp_g)), -128, 127)
// 4 VALU ops per (elem, group): fma, rndne, med3, fma -> ~6.8 us VALU, under the
// ~15 us memory stream. fma contraction is within threshold: a boundary flip
// perturbs out by <= max_g sw_g/s_g ~ 0.05 < 0.104 (round-9 analysis).
__global__ __launch_bounds__(128) void k_apply(const float* __restrict__ x,
                                               const float* __restrict__ wq,
                                               const float* __restrict__ offv,
                                               const float* __restrict__ scv,
                                               const float* __restrict__ zpv,
                                               float* __restrict__ out) {
    const int c = blockIdx.x & (C_ - 1);          // row = b*C_ + c
    float s[G_], nz[G_], w[G_];
#pragma unroll
    for (int g = 0; g < G_; ++g) {
        s[g]  = scv[g];
        nz[g] = -zpv[g];
        w[g]  = wq[g * C_ + c];
    }
    const float offc = offv[c];
    const size_t base = (size_t)blockIdx.x * (L_ / 4) + threadIdx.x;

    fx4 xv[8];
#pragma unroll
    for (int i = 0; i < 8; ++i)                   // issue all loads first
        xv[i] = ((const fx4*)x)[base + i * 128];

#pragma unroll
    for (int i = 0; i < 8; ++i) {
        fx4 rv;
#pragma unroll
        for (int k = 0; k < 4; ++k) {
            float acc = offc;
#pragma unroll
            for (int g = 0; g < G_; ++g) {
                float t = fmaf(s[g], xv[i][k], nz[g]);        // v_fma
                float q = rintf(t);                           // v_rndne
                q = __builtin_amdgcn_fmed3f(q, -128.0f, 127.0f); // v_med3
                acc = fmaf(w[g], q, acc);                     // v_fma
            }
            rv[k] = acc;
        }
        ((fx4*)out)[base + i * 128] = rv;         // plain cached store
    }
}

extern "C" void kernel_launch(void* const* d_in, const int* in_sizes, int n_in,
                              void* d_out, int out_size, void* d_ws, size_t ws_size,
                              hipStream_t stream) {
    const float* x = (const float*)d_in[0];       // [32,128,4096]
    const float* alpha = (const float*)d_in[1];   // [8,128]
    float* out = (float*)d_out;
    float* ws = (float*)d_ws;

    float* pmin = ws;              // [C_*B_] = 4096
    float* pmax = ws + 4096;       // 4096
    float* wq   = ws + 8192;       // [G_*C_] = 1024
    float* offv = ws + 9216;       // 128
    float* scv  = ws + 9344;       // 8
    float* zpv  = ws + 9352;       // 8

    k_minmax<<<ROWS / 4, 256, 0, stream>>>(x, pmin, pmax);
    k_prep<<<1, 128, 0, stream>>>(pmin, pmax, alpha, wq, offv, scv, zpv);
    k_apply<<<ROWS, 128, 0, stream>>>(x, wq, offv, scv, zpv, out);
}